// Round 1
// baseline (128.642 us; speedup 1.0000x reference)
//
#include <hip/hip_runtime.h>
#include <math.h>

#define BATCH 2
#define NPTS  1024
#define NC    32
#define DIN   8
#define DOUT  8
#define BCHUNK 16          // b-values per block; 512 blocks total -> 2 blocks/CU
#define R_MAX_F 3.5f

// ---------------------------------------------------------------------------
// Kernel 1: g[z,b,c,i] = sum_j W[c,i,j] * features[z,b,j]
// 512K outputs, one thread each. Trivial cost (~couple µs).
// ---------------------------------------------------------------------------
__global__ void g_kernel(const float* __restrict__ feat,
                         const float* __restrict__ W,
                         float* __restrict__ g) {
    int idx = blockIdx.x * blockDim.x + threadIdx.x;
    if (idx >= BATCH * NPTS * NC * DOUT) return;
    int i  = idx & 7;          // d_out index
    int c  = (idx >> 3) & 31;  // basis index
    int zb = idx >> 8;         // z*NPTS + b
    const float* f = feat + zb * DIN;
    const float* w = W + (c * DOUT + i) * DIN;   // W[c][i][:]
    float s = 0.f;
#pragma unroll
    for (int j = 0; j < DIN; ++j) s = fmaf(w[j], f[j], s);
    g[idx] = s;
}

// ---------------------------------------------------------------------------
// Kernel 2: out[z,a,i] += (1/sqrt(n)) * sum_{b in chunk} sum_c basis * g[z,b,c,i]
// Thread = one 'a'. b is wave-uniform -> geo[z,b] and g[z,b,c,i] become
// scalar (SGPR) loads broadcast to all lanes; per-block g traffic = 16 KB.
// ---------------------------------------------------------------------------
__global__ __launch_bounds__(256) void conv_kernel(
        const float* __restrict__ geo,
        const float* __restrict__ g,
        const int*   __restrict__ n_norm,
        float*       __restrict__ out) {
    const int nchunks = NPTS / BCHUNK;        // 64
    int bid   = blockIdx.x;
    int chunk = bid & (nchunks - 1);
    int rest  = bid >> 6;
    int atile = rest & 3;                     // 4 tiles of 256 a's
    int z     = rest >> 2;
    int a     = atile * 256 + threadIdx.x;

    const float* geoz = geo + (size_t)z * NPTS * 3;
    float ax = geoz[a * 3 + 0];
    float ay = geoz[a * 3 + 1];
    float az = geoz[a * 3 + 2];

    float acc[DOUT];
#pragma unroll
    for (int i = 0; i < DOUT; ++i) acc[i] = 0.f;

    const float invw = (float)(NC - 1) / R_MAX_F;   // 1/width
    const float* gz = g + (size_t)z * NPTS * NC * DOUT;

    int b0 = chunk * BCHUNK;
    for (int b = b0; b < b0 + BCHUNK; ++b) {
        // wave-uniform loads (scalar path)
        float bx = geoz[b * 3 + 0];
        float by = geoz[b * 3 + 1];
        float bz = geoz[b * 3 + 2];
        float dx = bx - ax, dy = by - ay, dz = bz - az;
        float d  = sqrtf(fmaf(dx, dx, fmaf(dy, dy, fmaf(dz, dz, 1e-12f))));
        float u  = d * invw;                  // distance in units of width
        const float* gb = gz + (size_t)b * NC * DOUT;
        for (int c = 0; c < NC; ++c) {
            float t = u - (float)c;
            float e = __expf(-(t * t));       // v_mul + v_mul + v_exp_f32
#pragma unroll
            for (int i = 0; i < DOUT; ++i)
                acc[i] = fmaf(e, gb[c * DOUT + i], acc[i]);
        }
    }

    float scale = 1.0f / sqrtf((float)n_norm[0]);   // exact: sqrt(1024)=32
    float* o = out + ((size_t)(z * NPTS + a)) * DOUT;
#pragma unroll
    for (int i = 0; i < DOUT; ++i) atomicAdd(&o[i], acc[i] * scale);
}

// ---------------------------------------------------------------------------
extern "C" void kernel_launch(void* const* d_in, const int* in_sizes, int n_in,
                              void* d_out, int out_size, void* d_ws, size_t ws_size,
                              hipStream_t stream) {
    const float* feat   = (const float*)d_in[0];   // [2,1024,8]
    const float* geo    = (const float*)d_in[1];   // [2,1024,3]
    const float* W      = (const float*)d_in[2];   // [32,8,8]
    const int*   n_norm = (const int*)  d_in[3];   // scalar 1024
    float* out = (float*)d_out;                    // [2,1024,8]
    float* g   = (float*)d_ws;                     // [2,1024,32,8] = 2 MB

    // out is re-poisoned before every launch -> zero it (atomic accumulate).
    hipMemsetAsync(d_out, 0, (size_t)out_size * sizeof(float), stream);

    int gtotal = BATCH * NPTS * NC * DOUT;         // 524288
    g_kernel<<<(gtotal + 255) / 256, 256, 0, stream>>>(feat, W, g);

    int grid = BATCH * 4 * (NPTS / BCHUNK);        // 512 blocks
    conv_kernel<<<grid, 256, 0, stream>>>(geo, g, n_norm, out);
}